// Round 6
// baseline (573.401 us; speedup 1.0000x reference)
//
#include <hip/hip_runtime.h>
#include <cstdint>
#include <cstddef>

#define NTOK 8192
#define C_ 1024
#define H_ 4096
#define E_ 8
#define YMAX 72  // max 128-row tiles over 8 experts: 8192/128 + 8 pad
#define RB_ (NTOK / 4)   // router blocks
#define TB1_ ((H_ / 64) * (C_ / 64) * E_)  // transpose-w1 blocks = 8192
#define TB2_ ((C_ / 64) * (H_ / 64) * E_)  // transpose-w2 blocks = 8192

typedef __attribute__((ext_vector_type(8))) short short8;
typedef __attribute__((ext_vector_type(4))) float f32x4;
typedef __attribute__((ext_vector_type(4))) unsigned int u32x4;

__device__ __forceinline__ uint16_t f2b(float f) {
    uint32_t x;
    __builtin_memcpy(&x, &f, 4);
    x = (x + 0x7fffu + ((x >> 16) & 1u)) >> 16;  // round-to-nearest-even
    return (uint16_t)x;
}

// tanh-form GELU, NaN-safe; |err vs erf-gelu| < ~3e-3 (threshold headroom 0.04)
__device__ __forceinline__ float gelu_f(float v) {
    float u = v * (0.7978845608028654f + 0.03567740814183f * v * v);
    float t = __expf(2.f * u);
    float th = 1.f - 2.f / (t + 1.f);
    return 0.5f * v * (1.f + th);
}

// barrier that does NOT drain vmcnt: only ds ops must land (lgkmcnt) before
// waves cross. Plain global_load->VGPR results are private; they may stay in
// flight across the barrier (this is the whole point of the depth-2 pipeline;
// __syncthreads would emit a vmcnt(0) drain and serialize the prefetch).
#define BAR_LGKM() do {                                             \
    __builtin_amdgcn_sched_barrier(0);                              \
    asm volatile("s_waitcnt lgkmcnt(0)" ::: "memory");              \
    __builtin_amdgcn_sched_barrier(0);                              \
    __builtin_amdgcn_s_barrier();                                   \
    __builtin_amdgcn_sched_barrier(0);                              \
} while (0)

// ------- transpose+convert tile body: w fp32 [E][K][N] -> wt bf16 [ez][N][K]
__device__ __forceinline__ void transpose_tile_body(
    const float* __restrict__ w, uint16_t* __restrict__ wt,
    int K, int N, int e, int ez, int n0, int k0, uint16_t (*tile)[66])
{
    int t = threadIdx.x;
#pragma unroll
    for (int i = 0; i < 4; i++) {
        int chunk = i * 256 + t;
        int r = chunk >> 4, c4 = chunk & 15;
        f32x4 v = *(const f32x4*)(w + (size_t)(e * K + k0 + r) * N + n0 + c4 * 4);
        uint32_t u0 = (uint32_t)f2b(v.x) | ((uint32_t)f2b(v.y) << 16);
        uint32_t u1 = (uint32_t)f2b(v.z) | ((uint32_t)f2b(v.w) << 16);
        *(uint32_t*)&tile[r][c4 * 4 + 0] = u0;
        *(uint32_t*)&tile[r][c4 * 4 + 2] = u1;
    }
    __syncthreads();
#pragma unroll
    for (int i = 0; i < 2; i++) {
        int chunk = i * 256 + t;
        int rn = chunk >> 3, ck = chunk & 7;
        uint32_t p[4];
#pragma unroll
        for (int j = 0; j < 4; j++) {
            uint32_t lo = tile[ck * 8 + 2 * j][rn];
            uint32_t hi = tile[ck * 8 + 2 * j + 1][rn];
            p[j] = lo | (hi << 16);
        }
        u32x4 v; v.x = p[0]; v.y = p[1]; v.z = p[2]; v.w = p[3];
        *(u32x4*)(wt + ((size_t)ez * N + n0 + rn) * K + k0 + ck * 8) = v;
    }
}

// standalone transpose (fallback tiers)
__global__ __launch_bounds__(256) void transpose_cvt_kernel(
    const float* __restrict__ w, uint16_t* __restrict__ wt,
    int K, int N, int ebase)
{
    __shared__ uint16_t tile[64][66];
    int ez = blockIdx.z;
    transpose_tile_body(w, wt, K, N, ebase + ez, ez,
                        blockIdx.x * 64, blockIdx.y * 64, tile);
}

// ------- fused launch A: router (+counts zero, +x->bf16) & transpose(w1) ----
// router: one wave per token, fp32 logits -> first-argmax (strict > = np).
// Blocks [0,RB_): router; [RB_, RB_+tblocks): w1 transpose (independent work).
__global__ __launch_bounds__(256) void router_t1_kernel(
    const float* __restrict__ x, const float* __restrict__ wr,
    const float* __restrict__ br, int* __restrict__ top1,
    uint16_t* __restrict__ xb, int* __restrict__ counts,
    const float* __restrict__ w1, uint16_t* __restrict__ wt1)
{
    __shared__ uint16_t tile[64][66];
    int bid = blockIdx.x;
    if (bid >= RB_) {
        int b = bid - RB_;                       // dim3(H/64=64, C/64=16, 8)
        int xq = b & 63, yq = (b >> 6) & 15, z = b >> 10;
        transpose_tile_body(w1, wt1, C_, H_, z, z, xq * 64, yq * 64, tile);
        return;
    }
    if (bid == 0 && threadIdx.x < E_) counts[threadIdx.x] = 0;
    int wid = threadIdx.x >> 6, lane = threadIdx.x & 63;
    int tok = bid * 4 + wid;
    const float* xrow = x + (size_t)tok * C_;
    uint16_t* xbrow = xb + (size_t)tok * C_;
    float acc[E_];
#pragma unroll
    for (int e = 0; e < E_; e++) acc[e] = 0.f;
#pragma unroll 4
    for (int i = 0; i < C_ / 64; i++) {
        int c = i * 64 + lane;
        float xv = xrow[c];
        xbrow[c] = f2b(xv);
        const f32x4 w0 = *(const f32x4*)(wr + (size_t)c * E_);
        const f32x4 w1v = *(const f32x4*)(wr + (size_t)c * E_ + 4);
#pragma unroll
        for (int e = 0; e < 4; e++) acc[e] += xv * w0[e];
#pragma unroll
        for (int e = 0; e < 4; e++) acc[4 + e] += xv * w1v[e];
    }
#pragma unroll
    for (int off = 32; off > 0; off >>= 1) {
#pragma unroll
        for (int e = 0; e < E_; e++) acc[e] += __shfl_xor(acc[e], off, 64);
    }
    if (lane == 0) {
        float best = acc[0] + br[0];
        int bi = 0;
#pragma unroll
        for (int e = 1; e < E_; e++) {
            float v = acc[e] + br[e];
            if (v > best) { best = v; bi = e; }
        }
        top1[tok] = bi;
    }
}

// two-level scatter: LDS histogram per block, 8 global atomics per block
__global__ __launch_bounds__(1024) void scatter_kernel(
    const int* __restrict__ top1, int* counts, int* __restrict__ idx)
{
    __shared__ int lc[E_], base[E_];
    int tid = threadIdx.x;
    if (tid < E_) lc[tid] = 0;
    __syncthreads();
    int t = blockIdx.x * 1024 + tid;
    int e = top1[t];
    int my = atomicAdd(&lc[e], 1);
    __syncthreads();
    if (tid < E_) base[tid] = atomicAdd(&counts[tid], lc[tid]);
    __syncthreads();
    idx[e * NTOK + base[e] + my] = t;
}

// ---------------- grouped GEMM: reg-staged depth-2 pipeline, dbuf LDS -------
// A bf16 [NTOK][K] gathered by token id; Bt bf16 [ez][N][K] k-contig.
// 128x128 tile, 256 thr = 4 waves (2x2), BK=32, per-wave 64x64 output.
// Depth-2: two named reg sets; set s is reloaded immediately after its
// ds_write, giving every set ~2 compute-phases of latency cover. Barriers
// are raw s_barrier + lgkmcnt(0) only -> prefetch loads stay in flight
// across barriers (T4); compiler emits precise vmcnt(4) at each ds_write.
// (e,mb) derived per block from counts (plan kernel eliminated).
// LDS chunk swizzle j^((r>>1)&3): fragment ds_read_b128 conflict-free (meas 0).
// T1 nb-major: each XCD owns GX/8 whole B-panel columns (panel L2-resident).
// Optional fused tail: blocks >= NWG transpose w2 (independent; feeds GEMM2).
template <int GX, int YB, int K, int N, typename OutT, bool GELU,
          int TB, int TNX, int TKY, int TK, int TN>
__global__ __launch_bounds__(256, 3) void gemm_kernel(
    const uint16_t* __restrict__ A, const uint16_t* __restrict__ Bt,
    const float* __restrict__ bias, OutT* __restrict__ Out,
    const int* __restrict__ counts, const int* __restrict__ idx,
    int e0, int ne, const float* __restrict__ wsrc, uint16_t* __restrict__ wdst)
{
    constexpr int BM = 128, BN = 128, NW = 256;
    constexpr int MR = 4;
    constexpr int NITER = K / 32;           // 32 or 128
    constexpr int NWG = GX * YB;
    static_assert(NWG % 8 == 0, "grid must be divisible by 8 XCDs");
    static_assert(NITER >= 4 && (NITER & 1) == 0, "NITER even >= 4");

    __shared__ __align__(16) uint16_t As[2][BM][32];
    __shared__ __align__(16) uint16_t Bs[2][BN][32];
    __shared__ uint16_t tile[TB > 0 ? 64 : 1][66];

    int bid = blockIdx.x;
    if constexpr (TB > 0) {
        if (bid >= NWG) {
            int b = bid - NWG;
            int xq = b % TNX, yq = (b / TNX) % TKY, z = b / (TNX * TKY);
            transpose_tile_body(wsrc, wdst, TK, TN, z, z, xq * 64, yq * 64, tile);
            return;
        }
    }

    // T1: XCD-chunked bijective swizzle, nb-major decode.
    int o = bid;
    int lid = (o & 7) * (NWG / 8) + (o >> 3);
    int nb = lid / YB;
    int tl = lid % YB;

    // derive (e, mb, cnt) from counts via register scan (plan eliminated)
    int cn[E_];
    {
        const int4 c0 = *(const int4*)counts;
        const int4 c1 = *(const int4*)(counts + 4);
        cn[0] = c0.x; cn[1] = c0.y; cn[2] = c0.z; cn[3] = c0.w;
        cn[4] = c1.x; cn[5] = c1.y; cn[6] = c1.z; cn[7] = c1.w;
    }
    int e = -1, mb = 0, cnt = 0;
#pragma unroll
    for (int q = 0; q < E_; ++q) {
        if (q >= e0 && q < e0 + ne && e < 0) {
            int nt = (cn[q] + 127) >> 7;
            if (tl < nt) { e = q; mb = tl; cnt = cn[q]; }
            else tl -= nt;
        }
    }
    if (e < 0) return;  // padding block
    int ez = e - e0;

    int t = threadIdx.x;
    int lane = t & 63, w = t >> 6;
    int wm = w >> 1, wn = w & 1;

    const int* idxe = idx + e * NTOK;

    f32x4 acc[MR][4];
#pragma unroll
    for (int mt = 0; mt < MR; mt++)
#pragma unroll
        for (int nt = 0; nt < 4; nt++) acc[mt][nt] = (f32x4)(0.f);

    const uint16_t* Bte = Bt + ((size_t)ez * N + (size_t)nb * BN) * K;

    // staging addresses: LDS chunk j (of 4 per 32-elem row) <- global chunk
    // j^((r>>1)&3) of the current 32-k window. 2 A + 2 B loads per thread.
    const uint16_t* aptr[2];
    const uint16_t* bptr[2];
#pragma unroll
    for (int i = 0; i < 2; i++) {
        int cid = i * NW + t;
        int r = cid >> 2, j = cid & 3;
        int s = mb * BM + r;
        int tk = idxe[(s < cnt) ? s : 0];
        aptr[i] = A + (size_t)tk * K + (j ^ ((r >> 1) & 3)) * 8;
    }
#pragma unroll
    for (int i = 0; i < 2; i++) {
        int cid = i * NW + t;
        int r = cid >> 2, j = cid & 3;
        bptr[i] = Bte + (size_t)r * K + (j ^ ((r >> 1) & 3)) * 8;
    }

    // two named register sets (rule 20: no runtime indexing)
    u32x4 ra0[2], rb0[2], ra1[2], rb1[2];
    auto loadA = [&](int kt) {
        int k0 = kt * 32;
        ra0[0] = *(const u32x4*)(aptr[0] + k0);
        ra0[1] = *(const u32x4*)(aptr[1] + k0);
        rb0[0] = *(const u32x4*)(bptr[0] + k0);
        rb0[1] = *(const u32x4*)(bptr[1] + k0);
    };
    auto loadB = [&](int kt) {
        int k0 = kt * 32;
        ra1[0] = *(const u32x4*)(aptr[0] + k0);
        ra1[1] = *(const u32x4*)(aptr[1] + k0);
        rb1[0] = *(const u32x4*)(bptr[0] + k0);
        rb1[1] = *(const u32x4*)(bptr[1] + k0);
    };
    auto writeA = [&]() {  // even steps -> buf 0
        *(u32x4*)(&As[0][0][0] + (size_t)t * 8) = ra0[0];
        *(u32x4*)(&As[0][0][0] + (size_t)(NW + t) * 8) = ra0[1];
        *(u32x4*)(&Bs[0][0][0] + (size_t)t * 8) = rb0[0];
        *(u32x4*)(&Bs[0][0][0] + (size_t)(NW + t) * 8) = rb0[1];
    };
    auto writeB = [&]() {  // odd steps -> buf 1
        *(u32x4*)(&As[1][0][0] + (size_t)t * 8) = ra1[0];
        *(u32x4*)(&As[1][0][0] + (size_t)(NW + t) * 8) = ra1[1];
        *(u32x4*)(&Bs[1][0][0] + (size_t)t * 8) = rb1[0];
        *(u32x4*)(&Bs[1][0][0] + (size_t)(NW + t) * 8) = rb1[1];
    };

    // fragment chunk: global chunk (lane>>4) stored at chunk^(((lane&15)>>1)&3)
    int cs = (((lane >> 4) ^ ((lane & 15) >> 1)) & 3) * 8;

    auto compute = [&](int sel) {
        short8 af[MR], bf[4];
#pragma unroll
        for (int mt = 0; mt < MR; mt++)
            af[mt] = *(const short8*)
                (&As[sel][0][0] + (wm * 64 + mt * 16 + (lane & 15)) * 32 + cs);
#pragma unroll
        for (int nt = 0; nt < 4; nt++)
            bf[nt] = *(const short8*)
                (&Bs[sel][0][0] + (wn * 64 + nt * 16 + (lane & 15)) * 32 + cs);
#pragma unroll
        for (int mt = 0; mt < MR; mt++)
#pragma unroll
            for (int nt = 0; nt < 4; nt++)
                acc[mt][nt] = __builtin_amdgcn_mfma_f32_16x16x32_bf16(
                    af[mt], bf[nt], acc[mt][nt], 0, 0, 0);
    };

    // prologue: preload steps 0,1; write step 0 into buf0.
    loadA(0);
    loadB(1);
    writeA();
    BAR_LGKM();

    // steady state: 2 steps per iteration, 1 barrier per step. Set s is
    // reloaded right after its ds_write was issued (regs free at issue).
    // Cover: loadA(kt+2) -> writeA = c(0)+writeB+bar+c(1); loadB(kt+3) ->
    // writeB(next iter) = c(1)+writeA+bar+c(0). Loads cross barriers (no
    // vmcnt drain); compiler waits vmcnt(4) at each write.
    int kt = 0;
    for (; kt + 3 < NITER; kt += 2) {
        loadA(kt + 2);
        __builtin_amdgcn_sched_barrier(0);
        compute(0);                 // step kt (buf0)
        __builtin_amdgcn_sched_barrier(0);
        writeB();                   // step kt+1 -> buf1
        BAR_LGKM();
        loadB(kt + 3);
        __builtin_amdgcn_sched_barrier(0);
        compute(1);                 // step kt+1 (buf1)
        __builtin_amdgcn_sched_barrier(0);
        writeA();                   // step kt+2 -> buf0
        BAR_LGKM();
    }
    // kt == NITER-2: buf0 holds step NITER-2; set B holds step NITER-1.
    compute(0);
    __builtin_amdgcn_sched_barrier(0);
    writeB();
    BAR_LGKM();
    compute(1);

    // epilogue: C/D layout col=lane&15, row=(lane>>4)*4+reg  [m89-verified]
    const float* be = bias + (size_t)e * N;
#pragma unroll
    for (int mt = 0; mt < MR; mt++) {
        int rbase = wm * 64 + mt * 16 + (lane >> 4) * 4;
#pragma unroll
        for (int r = 0; r < 4; r++) {
            int row = rbase + r;
            int s = mb * BM + row;
            if (s < cnt) {
                int tk = idxe[s];
#pragma unroll
                for (int nt = 0; nt < 4; nt++) {
                    int gcol = nb * BN + wn * 64 + nt * 16 + (lane & 15);
                    float v = acc[mt][nt][r] + be[gcol];
                    if (GELU) v = gelu_f(v);
                    if constexpr (sizeof(OutT) == 2)
                        Out[(size_t)tk * N + gcol] = (OutT)f2b(v);
                    else
                        Out[(size_t)tk * N + gcol] = v;
                }
            }
        }
    }
}

extern "C" void kernel_launch(void* const* d_in, const int* in_sizes, int n_in,
                              void* d_out, int out_size, void* d_ws, size_t ws_size,
                              hipStream_t stream)
{
    const float* x  = (const float*)d_in[0];
    const float* wr = (const float*)d_in[1];
    const float* br = (const float*)d_in[2];
    const float* b1 = (const float*)d_in[4];
    const float* w1 = (const float*)d_in[3];
    const float* w2 = (const float*)d_in[5];
    const float* b2 = (const float*)d_in[6];
    float* out = (float*)d_out;

    char* ws = (char*)d_ws;
    int* counts    = (int*)ws;                          // 32 B
    int* top1      = (int*)(ws + 1024);                 // 32 KiB
    int* idx       = (int*)(ws + 64 * 1024);            // 256 KiB
    uint16_t* xb   = (uint16_t*)(ws + ((size_t)1 << 20));   // 16 MiB
    uint16_t* hbuf = (uint16_t*)(ws + ((size_t)17 << 20));  // 64 MiB
    uint16_t* wT1  = (uint16_t*)(ws + ((size_t)81 << 20));  // 64 MiB (or 32 in small)
    uint16_t* wT2  = (uint16_t*)(ws + ((size_t)145 << 20)); // 64 MiB (tier1 only)

    bool t1 = ws_size >= ((size_t)209 << 20);  // wT1+wT2 coexist -> full fusion
    bool t2 = ws_size >= ((size_t)145 << 20);  // single 64-MiB wT

    if (t1) {
        hipLaunchKernelGGL(router_t1_kernel, dim3(RB_ + TB1_), dim3(256), 0,
                           stream, x, wr, br, top1, xb, counts, w1, wT1);
        hipLaunchKernelGGL(scatter_kernel, dim3(NTOK / 1024), dim3(1024), 0,
                           stream, top1, counts, idx);
        // GEMM1 (+fused transpose of w2 -> wT2 in the tail blocks)
        hipLaunchKernelGGL((gemm_kernel<H_ / 128, YMAX, C_, H_, uint16_t, true,
                                        TB2_, C_ / 64, H_ / 64, H_, C_>),
                           dim3(H_ / 128 * YMAX + TB2_), dim3(256), 0, stream,
                           xb, wT1, b1, hbuf, counts, idx, 0, E_, w2, wT2);
        hipLaunchKernelGGL((gemm_kernel<C_ / 128, YMAX, H_, C_, float, false,
                                        0, 1, 1, 1, 1>),
                           dim3(C_ / 128 * YMAX), dim3(256), 0, stream,
                           hbuf, wT2, b2, out, counts, idx, 0, E_,
                           (const float*)nullptr, (uint16_t*)nullptr);
    } else if (t2) {
        hipLaunchKernelGGL(router_t1_kernel, dim3(RB_ + TB1_), dim3(256), 0,
                           stream, x, wr, br, top1, xb, counts, w1, wT1);
        hipLaunchKernelGGL(scatter_kernel, dim3(NTOK / 1024), dim3(1024), 0,
                           stream, top1, counts, idx);
        hipLaunchKernelGGL((gemm_kernel<H_ / 128, YMAX, C_, H_, uint16_t, true,
                                        0, 1, 1, 1, 1>),
                           dim3(H_ / 128 * YMAX), dim3(256), 0, stream,
                           xb, wT1, b1, hbuf, counts, idx, 0, E_,
                           (const float*)nullptr, (uint16_t*)nullptr);
        hipLaunchKernelGGL(transpose_cvt_kernel, dim3(C_ / 64, H_ / 64, E_),
                           dim3(256), 0, stream, w2, wT1, H_, C_, 0);
        hipLaunchKernelGGL((gemm_kernel<C_ / 128, YMAX, H_, C_, float, false,
                                        0, 1, 1, 1, 1>),
                           dim3(C_ / 128 * YMAX), dim3(256), 0, stream,
                           hbuf, wT1, b2, out, counts, idx, 0, E_,
                           (const float*)nullptr, (uint16_t*)nullptr);
    } else {
        // small-ws fallback: router only (no fused T1), per-4-expert halves
        hipLaunchKernelGGL(router_t1_kernel, dim3(RB_), dim3(256), 0,
                           stream, x, wr, br, top1, xb, counts, w1, wT1);
        hipLaunchKernelGGL(scatter_kernel, dim3(NTOK / 1024), dim3(1024), 0,
                           stream, top1, counts, idx);
        for (int c = 0; c < 2; c++) {
            hipLaunchKernelGGL(transpose_cvt_kernel, dim3(H_ / 64, C_ / 64, 4),
                               dim3(256), 0, stream, w1, wT1, C_, H_, c * 4);
            hipLaunchKernelGGL((gemm_kernel<H_ / 128, YMAX, C_, H_, uint16_t, true,
                                            0, 1, 1, 1, 1>),
                               dim3(H_ / 128 * YMAX), dim3(256), 0, stream,
                               xb, wT1, b1, hbuf, counts, idx, c * 4, 4,
                               (const float*)nullptr, (uint16_t*)nullptr);
        }
        for (int c = 0; c < 2; c++) {
            hipLaunchKernelGGL(transpose_cvt_kernel, dim3(C_ / 64, H_ / 64, 4),
                               dim3(256), 0, stream, w2, wT1, H_, C_, c * 4);
            hipLaunchKernelGGL((gemm_kernel<C_ / 128, YMAX, H_, C_, float, false,
                                            0, 1, 1, 1, 1>),
                               dim3(C_ / 128 * YMAX), dim3(256), 0, stream,
                               hbuf, wT1, b2, out, counts, idx, c * 4, 4,
                               (const float*)nullptr, (uint16_t*)nullptr);
        }
    }
}